// Round 9
// baseline (247.334 us; speedup 1.0000x reference)
//
#include <hip/hip_runtime.h>

#define LSIZE 24
#define VOL (LSIZE*LSIZE*LSIZE*LSIZE)       // 331776 sites
#define NLINES (LSIZE*LSIZE*LSIZE)          // 13824 lines per direction
#define LPW 8                               // lines per wave (one octet-tile)
#define WPB 4                               // waves per block (independent, no barriers)
#define TPB 256
#define OCT (NLINES/LPW)                    // 1728 tiles per direction
#define OBUF 1152                           // dwords per wave j-slice buffer (2*8*8*9)

// (o_re,o_im) = a * b, complex 3x3 matmul (row-major). Output must not alias inputs.
__device__ __forceinline__ void cmul(const float* __restrict__ ar, const float* __restrict__ ai,
                                     const float* __restrict__ br, const float* __restrict__ bi,
                                     float* __restrict__ or_, float* __restrict__ oi_) {
#pragma unroll
  for (int i = 0; i < 3; ++i) {
#pragma unroll
    for (int j = 0; j < 3; ++j) {
      float sr = 0.f, si = 0.f;
#pragma unroll
      for (int m = 0; m < 3; ++m) {
        float x = ar[i*3+m], y = ai[i*3+m];
        float u = br[m*3+j], v = bi[m*3+j];
        sr = fmaf(x, u, sr);
        sr = fmaf(-y, v, sr);
        si = fmaf(x, v, si);
        si = fmaf(y, u, si);
      }
      or_[i*3+j] = sr;
      oi_[i*3+j] = si;
    }
  }
}

__device__ __forceinline__ void cp9(float* dr, float* di, const float* sr, const float* si) {
#pragma unroll
  for (int e = 0; e < 9; ++e) { dr[e] = sr[e]; di[e] = si[e]; }
}

__device__ __forceinline__ void setid(float* r, float* im) {
#pragma unroll
  for (int e = 0; e < 9; ++e) { r[e] = (e == 0 || e == 4 || e == 8) ? 1.f : 0.f; im[e] = 0.f; }
}

__device__ __forceinline__ void shup(float* dr, float* di, const float* sr, const float* si, int delta) {
#pragma unroll
  for (int e = 0; e < 9; ++e) {
    dr[e] = __shfl_up(sr[e], (unsigned)delta, 64);
    di[e] = __shfl_up(si[e], (unsigned)delta, 64);
  }
}
__device__ __forceinline__ void shdn(float* dr, float* di, const float* sr, const float* si, int delta) {
#pragma unroll
  for (int e = 0; e < 9; ++e) {
    dr[e] = __shfl_down(sr[e], (unsigned)delta, 64);
    di[e] = __shfl_down(si[e], (unsigned)delta, 64);
  }
}

// One tile (8 lines) per wave; 4 independent waves per block; zero __syncthreads.
//   compute : register-resident chunk scan (R1 core, 5 cmul/site). Thread
//             (tl,ll) owns links 3tl..3tl+2 of line ll. B = U0*U1*U2; in-wave
//             shuffle scans; R = (B_{t+1}..B_7)(B_0..B_{t-1});
//             out0=B*R, out1=S1*(R*U0), out2=U2*(R*A1).
//   loads   : direct scattered (R1-proven ~5% byte cost, L2/L3-absorbed).
//   stores  : mu!=3 via per-wave 4.6KB LDS j-slice transpose (write 2-way
//             bank-free, wave-local lgkmcnt sync, read float4, 288B-contiguous
//             16B-aligned global runs). mu==3 stores directly (contiguous).
// Caps: LDS 18432B -> 8 wg/CU; VGPR<=128 -> 16 waves/CU; supply 27 waves/CU.
__global__ __launch_bounds__(TPB, 4) void polyakov_js(
    const float* __restrict__ U_re, const float* __restrict__ U_im,
    float* __restrict__ out) {
  __shared__ __align__(16) float obuf[WPB * OBUF];   // 18432 B

  const int lane = threadIdx.x & 63;
  const int wv   = threadIdx.x >> 6;
  const int O    = blockIdx.x * WPB + wv;            // tile id (mu uniform per wave)
  const int mu   = O / OCT;
  const int l0   = (O - mu * OCT) * LPW;

  int tl, ll, sh;
  if (mu == 3) { tl = lane & 7; ll = lane >> 3; sh = 1; }
  else         { tl = lane >> 3; ll = lane & 7; sh = 8; }

  const int l  = l0 + ll;
  const int cC = l % LSIZE;
  const int cB = (l / LSIZE) % LSIZE;
  const int cA = l / (LSIZE*LSIZE);

  int x0, x1, x2, x3, st;
  if (mu == 0)      { x0 = 0;  x1 = cA; x2 = cB; x3 = cC; st = LSIZE*LSIZE*LSIZE; }
  else if (mu == 1) { x0 = cA; x1 = 0;  x2 = cB; x3 = cC; st = LSIZE*LSIZE; }
  else if (mu == 2) { x0 = cA; x1 = cB; x2 = 0;  x3 = cC; st = LSIZE; }
  else              { x0 = cA; x1 = cB; x2 = cC; x3 = 0;  st = 1; }
  const int s0 = ((x0*LSIZE + x1)*LSIZE + x2)*LSIZE + x3;
  const int k0 = 3 * tl;

  const float* __restrict__ gR = U_re + (size_t)mu * (VOL*9);
  const float* __restrict__ gI = U_im + (size_t)mu * (VOL*9);
  float* __restrict__ oR = out + (size_t)mu * (VOL*9);
  float* __restrict__ oI = out + (size_t)(4 + mu) * (VOL*9);

  auto ldU = [&](int kk, float* r, float* im_) {
    const float* p = gR + (size_t)(s0 + kk*st) * 9;
    const float* q = gI + (size_t)(s0 + kk*st) * 9;
#pragma unroll
    for (int e = 0; e < 9; ++e) { r[e] = p[e]; im_[e] = q[e]; }
  };

  float* wb = obuf + wv * OBUF;

  // emit out_j: mu==3 direct (contiguous), else j-slice LDS transpose
  auto emit = [&](const float* Vr, const float* Vi, int j) {
    if (mu == 3) {
      float* pr = oR + (size_t)(s0 + k0 + j) * 9;
      float* pi = oI + (size_t)(s0 + k0 + j) * 9;
#pragma unroll
      for (int e = 0; e < 9; ++e) { pr[e] = Vr[e]; pi[e] = Vi[e]; }
    } else {
      // previous slice's ds_reads complete -> buffer reusable (wave-local)
      asm volatile("s_waitcnt lgkmcnt(0)" ::: "memory");
      __builtin_amdgcn_sched_barrier(0);
      const int wbase = tl * 72 + ll * 9;
#pragma unroll
      for (int e = 0; e < 9; ++e) {
        wb[wbase + e]       = Vr[e];
        wb[576 + wbase + e] = Vi[e];
      }
      asm volatile("s_waitcnt lgkmcnt(0)" ::: "memory");   // all 64 lanes' writes done
      __builtin_amdgcn_sched_barrier(0);
      // read out + store: 288 float4 chunks; global runs 288B contiguous, 16B aligned
      const int s00x9 = (s0 - ll) * 9;                     // ll==0 base (e2==1 for mu!=3)
#pragma unroll
      for (int p = 0; p < 5; ++p) {
        int c = p * 64 + lane;
        if (c < 288) {
          int arr  = c >= 144;
          int ca   = c - (arr ? 144 : 0);
          int slab = ca / 18;
          int rem  = ca - slab * 18;
          float4 v = *(const float4*)(wb + arr * 576 + slab * 72 + rem * 4);
          float* g = (arr ? oI : oR) + (size_t)(s00x9 + (3 * slab + j) * st * 9 + rem * 4);
          *(float4*)g = v;
        }
      }
    }
  };

  // ---- local chunk products ----
  float U0r[9], U0i[9], U1r[9], U1i[9], U2r[9], U2i[9];
  ldU(k0 + 0, U0r, U0i);
  ldU(k0 + 1, U1r, U1i);
  ldU(k0 + 2, U2r, U2i);

  float A1r[9], A1i[9], Br[9], Bi[9], S1r[9], S1i[9];
  cmul(U0r, U0i, U1r, U1i, A1r, A1i);    // A1 = U0*U1
  cmul(A1r, A1i, U2r, U2i, Br,  Bi);     // B  = U0*U1*U2
  cmul(U1r, U1i, U2r, U2i, S1r, S1i);    // S1 = U1*U2  (U1 dead)

  float Yr[9], Yi[9], Tr[9], Ti[9];

  // ---- inclusive prefix scan -> exclusive end P = B_0..B_{t-1} ----
  float Pr[9], Pi[9];
  {
    float Xr[9], Xi[9];
    cp9(Xr, Xi, Br, Bi);
#pragma unroll
    for (int d = 1; d < 8; d <<= 1) {
      shup(Yr, Yi, Xr, Xi, d * sh);
      if (tl >= d) { cmul(Yr, Yi, Xr, Xi, Tr, Ti); cp9(Xr, Xi, Tr, Ti); }
    }
    shup(Pr, Pi, Xr, Xi, sh);
    if (tl == 0) setid(Pr, Pi);
  }
  // ---- inclusive suffix scan -> exclusive end Q = B_{t+1}..B_7 ; R = Q*P ----
  float Rr[9], Ri[9];
  {
    float Zr[9], Zi[9];
    cp9(Zr, Zi, Br, Bi);
#pragma unroll
    for (int d = 1; d < 8; d <<= 1) {
      shdn(Yr, Yi, Zr, Zi, d * sh);
      if (tl + d < 8) { cmul(Zr, Zi, Yr, Yi, Tr, Ti); cp9(Zr, Zi, Tr, Ti); }
    }
    shdn(Yr, Yi, Zr, Zi, sh);            // Q
    if (tl == 7) setid(Yr, Yi);
    cmul(Yr, Yi, Pr, Pi, Rr, Ri);        // R = Q*P  (P dead)
  }

  // ---- outputs ----
  cmul(Br, Bi, Rr, Ri, Tr, Ti);          // out0 = B*R   (B dead)
  emit(Tr, Ti, 0);

  cmul(Rr, Ri, U0r, U0i, Yr, Yi);        // Y = R*U0
  cmul(S1r, S1i, Yr, Yi, Tr, Ti);        // out1 = S1*(R*U0)
  emit(Tr, Ti, 1);

  cmul(Rr, Ri, A1r, A1i, Yr, Yi);        // Y = R*A1
  cmul(U2r, U2i, Yr, Yi, Tr, Ti);        // out2 = U2*(R*A1)
  emit(Tr, Ti, 2);
}

extern "C" void kernel_launch(void* const* d_in, const int* in_sizes, int n_in,
                              void* d_out, int out_size, void* d_ws, size_t ws_size,
                              hipStream_t stream) {
  const float* U_re = (const float*)d_in[0];
  const float* U_im = (const float*)d_in[1];
  float* out = (float*)d_out;
  int nblocks = 4 * OCT / WPB;   // 1728 blocks x 256 threads (4 independent waves)
  hipLaunchKernelGGL(polyakov_js, dim3(nblocks), dim3(TPB), 0, stream, U_re, U_im, out);
}